// Round 12
// baseline (135.492 us; speedup 1.0000x reference)
//
#include <hip/hip_runtime.h>
#include <math.h>

#define BB 4
#define CC 64
#define HH_ 128
#define WW 128
#define HPW (HH_*WW)     // 16384
#define KH 64
#define KW 64
#define KSZ 7
#define AA 16
#define EPSV 1e-5f
#define KTOT 448         // 7*64

typedef __attribute__((ext_vector_type(8))) short bf16x8;
typedef __attribute__((ext_vector_type(4))) float f32x4;
typedef unsigned short ushort_t;

__device__ __forceinline__ float sigm(float x){ return 1.0f/(1.0f+expf(-x)); }
__device__ __forceinline__ unsigned short f2bf(float f){
  unsigned u = __float_as_uint(f);
  return (unsigned short)((u + 0x7fffu + ((u>>16)&1u)) >> 16);
}
__device__ __forceinline__ bf16x8 lerp8(float4 a0, float4 a1, float4 b0, float4 b1, float wr){
  bf16x8 r;
  r[0]=(short)f2bf(a0.x + wr*(b0.x-a0.x));
  r[1]=(short)f2bf(a0.y + wr*(b0.y-a0.y));
  r[2]=(short)f2bf(a0.z + wr*(b0.z-a0.z));
  r[3]=(short)f2bf(a0.w + wr*(b0.w-a0.w));
  r[4]=(short)f2bf(a1.x + wr*(b1.x-a1.x));
  r[5]=(short)f2bf(a1.y + wr*(b1.y-a1.y));
  r[6]=(short)f2bf(a1.z + wr*(b1.z-a1.z));
  r[7]=(short)f2bf(a1.w + wr*(b1.w-a1.w));
  return r;
}

// ---------------- K1: prep + DWT-HH + mean partials (512 x 512) ----------------
__global__ __launch_bounds__(512) void k_dwt0(const float* __restrict__ x,
  const float* __restrict__ dsw, const float* __restrict__ offw,
  float* __restrict__ HHb, float* __restrict__ partial,
  ushort_t* __restrict__ dsWbf, ushort_t* __restrict__ offAbf)
{
  int t = threadIdx.x; int wg = blockIdx.x;
  int idx = wg*512 + t;
  if(idx < CC*KTOT){
    int co = idx/KTOT; int K = idx%KTOT; int k = K>>6; int ci = K&63;
    dsWbf[idx] = f2bf(dsw[(size_t)(co*CC+ci)*KSZ + k]);
  } else {
    int j2 = idx - CC*KTOT;
    if(j2 < 18*16*32){
      int kl = j2&31; int co = (j2>>5)&15; int s = j2>>9;
      int tap = s>>1; int ci = (s&1)*32 + kl;
      float v = 0.f;
      if(co<KSZ) v = offw[((size_t)co*CC + ci)*9 + tap];
      offAbf[j2] = f2bf(v);
    }
  }
  int lane = t&63, wid = t>>6;
  int e0 = wg*2048 + t*4;
  int bc = e0>>12; int h2 = (e0>>6)&63; int w0 = e0&63;
  const float* xp = x + (size_t)bc*HPW;
  float4 a0 = *(const float4*)(xp + (2*h2)*WW + 2*w0);
  float4 a1 = *(const float4*)(xp + (2*h2)*WW + 2*w0 + 4);
  float4 b0 = *(const float4*)(xp + (2*h2+1)*WW + 2*w0);
  float4 b1 = *(const float4*)(xp + (2*h2+1)*WW + 2*w0 + 4);
  float4 hh;
  hh.x = 0.5f*(a0.x - b0.x - a0.y + b0.y);
  hh.y = 0.5f*(a0.z - b0.z - a0.w + b0.w);
  hh.z = 0.5f*(a1.x - b1.x - a1.y + b1.y);
  hh.w = 0.5f*(a1.z - b1.z - a1.w + b1.w);
  *(float4*)(HHb + e0) = hh;
  float s = a0.x+a0.y+a0.z+a0.w + a1.x+a1.y+a1.z+a1.w
          + b0.x+b0.y+b0.z+b0.w + b1.x+b1.y+b1.z+b1.w;
  for(int o=32;o>0;o>>=1) s += __shfl_down(s,o);
  __shared__ float ls[8];
  if(lane==0) ls[wid] = s;
  __syncthreads();
  if(t==0){
    float tot=0.f;
    #pragma unroll
    for(int k2=0;k2<8;k2++) tot += ls[k2];
    partial[wg] = tot;
  }
}

// ---------------- K2: attention + weff, grid (b,o), 64 thr ----------------
__global__ __launch_bounds__(64) void k_weff2(const float* __restrict__ partial,
  const float* __restrict__ w, const float* __restrict__ ratio_p,
  const float* __restrict__ o1fc, const float* __restrict__ o1g,const float* __restrict__ o1b,
  const float* __restrict__ o1m,const float* __restrict__ o1v,
  const float* __restrict__ o1cw,const float* __restrict__ o1cb,
  const float* __restrict__ o1fw,const float* __restrict__ o1fb,
  const float* __restrict__ o2fc, const float* __restrict__ o2g,const float* __restrict__ o2b,
  const float* __restrict__ o2m,const float* __restrict__ o2v,
  const float* __restrict__ o2cw,const float* __restrict__ o2cb,
  const float* __restrict__ o2fw,const float* __restrict__ o2fb,
  const float* __restrict__ spw,const float* __restrict__ spb,
  float* __restrict__ weff)
{
  int bo = blockIdx.x; int b = bo>>6, o = bo&63; int ci = threadIdx.x;
  int bc = b*CC+ci;
  float g_own = (partial[2*bc] + partial[2*bc+1]) * (1.0f/HPW);
  float d1=o1cb[ci], d2=o1fb[ci], d3=o2cb[ci], d4=o2fb[ci];
  float sspacc[9];
  #pragma unroll
  for(int e=0;e<9;e++) sspacc[e]=spb[e];
  for(int j=0;j<AA;j++){
    float p1 = g_own * o1fc[j*CC+ci];
    float p2 = g_own * o2fc[j*CC+ci];
    #pragma unroll
    for(int off=32;off>0;off>>=1){ p1+=__shfl_xor(p1,off); p2+=__shfl_xor(p2,off); }
    p1 = (p1-o1m[j])*rsqrtf(o1v[j]+EPSV)*o1g[j]+o1b[j]; p1=fmaxf(p1,0.f);
    p2 = (p2-o2m[j])*rsqrtf(o2v[j]+EPSV)*o2g[j]+o2b[j]; p2=fmaxf(p2,0.f);
    d1 += p1*o1cw[ci*AA+j]; d2 += p1*o1fw[ci*AA+j];
    d3 += p2*o2cw[ci*AA+j]; d4 += p2*o2fw[ci*AA+j];
    #pragma unroll
    for(int e=0;e<9;e++) sspacc[e] += p2*spw[e*AA+j];
  }
  float sc1v=sigm(d1), sc2v=sigm(d3);
  float sf1o=__shfl(sigm(d2),o), sf2o=__shfl(sigm(d4),o);
  const float* wp = w + (size_t)(o*CC+ci)*9;
  float w9[9]; float m=0.f;
  #pragma unroll
  for(int e=0;e<9;e++){ w9[e]=wp[e]; m+=w9[e]; }
  m *= (1.0f/9.0f);
  float S1 = m * sc1v;
  float M[9];
  #pragma unroll
  for(int e=0;e<9;e++) M[e] = (w9[e]-m)*sc2v;
  #pragma unroll
  for(int off=32; off>0; off>>=1){
    S1 += __shfl_xor(S1, off);
    #pragma unroll
    for(int e=0;e<9;e++) M[e] += __shfl_xor(M[e], off);
  }
  if(ci==0){
    const float Dm[3][3] = {{2.f,2.f,2.f},{1.7320508075688772f,0.f,-1.7320508075688772f},{1.f,-2.f,1.f}};
    const float Di[3][3] = {{0.16666666666666666f,0.28867513459481287f,0.16666666666666666f},
                            {0.16666666666666666f,0.f,-0.3333333333333333f},
                            {0.16666666666666666f,-0.28867513459481287f,0.16666666666666666f}};
    float U[3][3], T[3][3], V[3][3], R[3][3];
    for(int k=0;k<3;k++)for(int n=0;n<3;n++) U[k][n]=Dm[k][0]*M[0*3+n]+Dm[k][1]*M[1*3+n]+Dm[k][2]*M[2*3+n];
    for(int k=0;k<3;k++)for(int l=0;l<3;l++) T[k][l]=(U[k][0]*Dm[l][0]+U[k][1]*Dm[l][1]+U[k][2]*Dm[l][2])*2.0f*sigm(sspacc[k*3+l]);
    for(int k=0;k<3;k++)for(int n=0;n<3;n++) V[k][n]=Di[k][0]*T[0][n]+Di[k][1]*T[1][n]+Di[k][2]*T[2][n];
    for(int k=0;k<3;k++)for(int l=0;l<3;l++) R[k][l]=V[k][0]*Di[l][0]+V[k][1]*Di[l][1]+V[k][2]*Di[l][2];
    float rr = ratio_p[0];
    float base = rr*4.0f*sf1o*S1;
    float w2f = (1.0f-rr)*4.0f*sf2o;
    #pragma unroll
    for(int e=0;e<9;e++) weff[(size_t)bo*9+e] = base + w2f*R[e/3][e%3];
  }
}

// ---------------- K3: iwt + transpose, 2 output rows per block ----------------
__global__ __launch_bounds__(256) void k_iwtT(const float* __restrict__ HHb,
  const float* __restrict__ x, const float* __restrict__ weff,
  float* __restrict__ outT, ushort_t* __restrict__ outTbf)
{
  __shared__ __align__(16) char smem[33024 + 16640];
  float* hs  = (float*)smem;             // [32][3][66]
  float* xt  = (float*)smem;             // [64][129] (reused after conv)
  float* d_s = (float*)(smem + 33024);   // [64][65]
  int wg = blockIdx.x; int b = wg>>6, h2 = wg&63;
  int t = threadIdx.x;
  #pragma unroll
  for(int half=0; half<2; ++half){
    for(int e=t; e<32*3*66; e+=256){
      int c_l = e/198; int rem = e - c_l*198; int r3 = rem/66; int wz = rem - r3*66;
      int r = h2 - 1 + r3; int w2 = wz - 1;
      int c = half*32 + c_l;
      float v = 0.f;
      if(r>=0 && r<KH && w2>=0 && w2<KW)
        v = HHb[((size_t)(b*CC+c))*(KH*KW) + r*KW + w2];
      hs[(c_l*3 + r3)*66 + wz] = v;
    }
    __syncthreads();
    {
      int c_l = t>>3, q = t&7;
      int c = half*32 + c_l;
      float wk[9];
      #pragma unroll
      for(int e=0;e<9;e++) wk[e] = weff[(size_t)(b*CC+c)*9+e];
      const float* hb = hs + c_l*198;
      #pragma unroll
      for(int j=0;j<8;j++){
        int w2 = q*8+j;
        float conv = 0.f;
        #pragma unroll
        for(int dh=0;dh<3;dh++){
          const float* hr = hb + dh*66 + w2;
          conv += wk[dh*3+0]*hr[0] + wk[dh*3+1]*hr[1] + wk[dh*3+2]*hr[2];
        }
        d_s[c*65+w2] = 0.5f*(conv - hb[1*66 + w2 + 1]);
      }
    }
    __syncthreads();
  }
  #pragma unroll
  for(int r=0;r<2;r++){
    int h = 2*h2 + r;
    for(int e=t; e<CC*WW; e+=256){
      int cc=e>>7, w=e&127;
      xt[cc*129+w] = x[((size_t)(b*CC+cc)*HH_+h)*WW + w];
    }
    __syncthreads();
    float* dst = outT + ((size_t)(b*HH_+h))*WW*CC;
    ushort_t* dstb = outTbf + ((size_t)(b*HH_+h))*130*CC;
    for(int e=t; e<CC*WW; e+=256){
      int w=e>>6, cc=e&63;
      float dv = d_s[cc*65+(w>>1)];
      float val = 2.f*xt[cc*129+w] + (((h + w)&1) ? -dv : dv);
      dst[e] = val;
      dstb[(w+1)*CC + cc] = f2bf(val);
    }
    if(t<128){ int cc=t&63; int side=t>>6; dstb[(size_t)side*129*CC + cc] = 0; }
    __syncthreads();
  }
}

// ---------------- K4: fused offset-conv + dy + deform-sample GEMM (direct-global B) ----------------
// wave wid owns w-tile [wid*16, +16); computes all 64 co. No LDS for samples, no GEMM barriers.
__global__ __launch_bounds__(512) void k_dsfused(const float* __restrict__ outT,
  const ushort_t* __restrict__ outTbf, const ushort_t* __restrict__ dsWbf,
  const ushort_t* __restrict__ offAbf, const float* __restrict__ offb,
  const float* __restrict__ obg, const float* __restrict__ obb,
  const float* __restrict__ obm, const float* __restrict__ obv,
  const float* __restrict__ dsb, float* __restrict__ yout, float* __restrict__ pstats)
{
  __shared__ int sb0[KSZ*128], sb1[KSZ*128];
  __shared__ float swr[KSZ*128];
  __shared__ float off_s[KSZ*128];
  __shared__ float dy_s[KSZ*128];
  int t = threadIdx.x;
  int wg = blockIdx.x; int sw = (wg&7)*64 + (wg>>3);   // XCD swizzle
  int b = sw>>7, h = sw&127;
  int lane = t&63, wid = t>>6;
  int arow = lane&15, kgrp = lane>>4;
  // ---- Phase A: offset conv (8 waves, wave = one 16-wide w tile) ----
  {
    f32x4 acc = (f32x4){0.f,0.f,0.f,0.f};
    #pragma unroll
    for(int s=0;s<18;s++){
      int tap = s>>1, chalf = s&1;
      int r = tap/3, dwp = tap%3;
      int hr = h - 1 + r;
      if(hr<0 || hr>=HH_) continue;
      bf16x8 aF = *(const bf16x8*)(offAbf + (s*16+arow)*32 + kgrp*8);
      const ushort_t* base = outTbf + ((size_t)(b*HH_+hr))*130*CC + chalf*32 + kgrp*8;
      int wp = (wid<<4) + arow + dwp;
      bf16x8 bF = *(const bf16x8*)(base + (size_t)wp*CC);
      acc = __builtin_amdgcn_mfma_f32_16x16x32_bf16(aF, bF, acc, 0,0,0);
    }
    #pragma unroll
    for(int r=0;r<4;r++){
      int co = kgrp*4+r;
      if(co<KSZ) off_s[co*128 + (wid<<4) + arow] = acc[r];
    }
  }
  __syncthreads();
  // ---- Phase B: BN + tanh + cumsum ----
  if(t<128){
    int w = t;
    float y[KSZ];
    #pragma unroll
    for(int k=0;k<KSZ;k++){
      float sc = obg[k]*rsqrtf(obv[k]+EPSV);
      float sh = obb[k]-obm[k]*sc;
      y[k] = tanhf((off_s[k*128+w]+offb[k])*sc+sh);
    }
    dy_s[      w]=y[0]+y[1]+y[2]; dy_s[128+w]=y[1]+y[2]; dy_s[256+w]=y[2];
    dy_s[384+w]=0.f; dy_s[512+w]=y[4]; dy_s[640+w]=y[4]+y[5]; dy_s[768+w]=y[4]+y[5]+y[6];
  }
  __syncthreads();
  // ---- Phase C: sample meta ----
  for(int e=t; e<KSZ*128; e+=512){
    int k = e>>7, w = e&127;
    float dv = dy_s[e];
    float r = fminf(fmaxf((float)h + dv, 0.f), 127.f);
    float rf = floorf(r); int r0=(int)rf; float wr=r-rf; int r1=min(r0+1,127);
    int c = min(max(w+k-3,0),127);
    sb0[k*128+w] = ((b*HH_+r0)*WW+c)*CC;
    sb1[k*128+w] = ((b*HH_+r1)*WW+c)*CC;
    swr[k*128+w] = wr;
  }
  __syncthreads();
  // ---- Phase D: barrier-free GEMM, B-frags direct from global ----
  int w = (wid<<4) + arow;
  f32x4 acc[4];
  #pragma unroll
  for(int cg=0;cg<4;cg++) acc[cg] = (f32x4){0.f,0.f,0.f,0.f};
  #pragma unroll
  for(int k=0;k<KSZ;k++){
    int e = k*128 + w;
    int b0 = sb0[e], b1 = sb1[e]; float wr = swr[e];
    int off = kgrp*8;
    const float* p0 = outT + b0 + off;
    const float* p1 = outT + b1 + off;
    const float* q0 = p0 + 32;
    const float* q1 = p1 + 32;
    float4 r0a = *(const float4*)(p0);
    float4 r0b = *(const float4*)(p0+4);
    float4 r1a = *(const float4*)(p1);
    float4 r1b = *(const float4*)(p1+4);
    float4 s0a = *(const float4*)(q0);
    float4 s0b = *(const float4*)(q0+4);
    float4 s1a = *(const float4*)(q1);
    float4 s1b = *(const float4*)(q1+4);
    bf16x8 bF0 = lerp8(r0a, r0b, r1a, r1b, wr);
    bf16x8 bF1 = lerp8(s0a, s0b, s1a, s1b, wr);
    #pragma unroll
    for(int cg=0;cg<4;cg++){
      const ushort_t* Wp = dsWbf + (size_t)((cg<<4)+arow)*KTOT + (k<<6) + kgrp*8;
      bf16x8 a0 = *(const bf16x8*)Wp;
      bf16x8 a1 = *(const bf16x8*)(Wp+32);
      acc[cg] = __builtin_amdgcn_mfma_f32_16x16x32_bf16(a0, bF0, acc[cg], 0,0,0);
      acc[cg] = __builtin_amdgcn_mfma_f32_16x16x32_bf16(a1, bF1, acc[cg], 0,0,0);
    }
  }
  // ---- epilogue: y + GN partials (per-wave w-tile) ----
  float vs[16], vq[16];
  #pragma unroll
  for(int cg=0;cg<4;cg++){
    #pragma unroll
    for(int r=0;r<4;r++){
      int co = (cg<<4) + kgrp*4 + r;
      float y = acc[cg][r] + dsb[co];
      int wcol = (wid<<4) + arow;
      yout[((size_t)(b*CC+co)*HH_ + h)*WW + wcol] = y;
      vs[cg*4+r] = y; vq[cg*4+r] = y*y;
    }
  }
  #pragma unroll
  for(int m=1;m<16;m<<=1){
    #pragma unroll
    for(int i=0;i<16;i++){ vs[i]+=__shfl_xor(vs[i],m); vq[i]+=__shfl_xor(vq[i],m); }
  }
  if(arow==0){
    #pragma unroll
    for(int cg=0;cg<4;cg++){
      #pragma unroll
      for(int r=0;r<4;r++){
        int co = (cg<<4)+kgrp*4+r;
        int pi = (b*CC+co)*1024 + h*8 + wid;
        pstats[pi] = vs[cg*4+r];
        pstats[262144+pi] = vq[cg*4+r];
      }
    }
  }
}

// ---------------- K5: reduce GN partials -> group stats ----------------
__global__ __launch_bounds__(256) void k_gnfin2(const float* __restrict__ pstats,
                                                float* __restrict__ gstat){
  int bg = blockIdx.x; int b = bg>>4, g = bg&15; int t = threadIdx.x;
  float s=0.f, q=0.f;
  #pragma unroll
  for(int c4=0;c4<4;c4++){
    int base = (b*CC + g*4+c4)*1024;
    for(int i=t;i<1024;i+=256){
      s += pstats[base + i];
      q += pstats[262144 + base + i];
    }
  }
  for(int o=32;o>0;o>>=1){ s+=__shfl_down(s,o); q+=__shfl_down(q,o); }
  __shared__ float ls[4], lq[4];
  if((t&63)==0){ ls[t>>6]=s; lq[t>>6]=q; }
  __syncthreads();
  if(t==0){
    float S=ls[0]+ls[1]+ls[2]+ls[3], Q=lq[0]+lq[1]+lq[2]+lq[3];
    float inv = 1.0f/(4.0f*HPW);
    float mu = S*inv; float var = Q*inv - mu*mu;
    gstat[bg*2]=mu; gstat[bg*2+1]=rsqrtf(var+EPSV);
  }
}

// ---------------- K6: apply GN + affine + relu in place ----------------
__global__ void k_gnapply(float* __restrict__ y, const float* __restrict__ gstat,
  const float* __restrict__ gg, const float* __restrict__ gb){
  int idx = blockIdx.x*256 + threadIdx.x;
  float4* p = (float4*)y;
  int bc = idx >> 12;
  int b = bc>>6, c = bc&63;
  int gi = b*16 + (c>>2);
  float mu = gstat[gi*2], rstd = gstat[gi*2+1];
  float sc = rstd*gg[c], sh = gb[c]-mu*sc;
  float4 v = p[idx];
  v.x = fmaxf(v.x*sc+sh, 0.f);
  v.y = fmaxf(v.y*sc+sh, 0.f);
  v.z = fmaxf(v.z*sc+sh, 0.f);
  v.w = fmaxf(v.w*sc+sh, 0.f);
  p[idx] = v;
}

extern "C" void kernel_launch(void* const* d_in, const int* in_sizes, int n_in,
                              void* d_out, int out_size, void* d_ws, size_t ws_size,
                              hipStream_t stream) {
  const float* x      = (const float*)d_in[0];
  const float* weight = (const float*)d_in[1];
  const float* ratio  = (const float*)d_in[2];
  const float* o1fc   = (const float*)d_in[3];
  const float* o1g    = (const float*)d_in[4];
  const float* o1b    = (const float*)d_in[5];
  const float* o1m    = (const float*)d_in[6];
  const float* o1v    = (const float*)d_in[7];
  const float* o1cw   = (const float*)d_in[8];
  const float* o1cb   = (const float*)d_in[9];
  const float* o1fw   = (const float*)d_in[10];
  const float* o1fb   = (const float*)d_in[11];
  const float* o2fc   = (const float*)d_in[12];
  const float* o2g    = (const float*)d_in[13];
  const float* o2b    = (const float*)d_in[14];
  const float* o2m    = (const float*)d_in[15];
  const float* o2v    = (const float*)d_in[16];
  const float* o2cw   = (const float*)d_in[17];
  const float* o2cb   = (const float*)d_in[18];
  const float* o2fw   = (const float*)d_in[19];
  const float* o2fb   = (const float*)d_in[20];
  const float* spw    = (const float*)d_in[21];
  const float* spb    = (const float*)d_in[22];
  const float* offw   = (const float*)d_in[23];
  const float* offb   = (const float*)d_in[24];
  const float* obg    = (const float*)d_in[25];
  const float* obb    = (const float*)d_in[26];
  const float* obm    = (const float*)d_in[27];
  const float* obv    = (const float*)d_in[28];
  const float* dsw    = (const float*)d_in[29];
  const float* dsb    = (const float*)d_in[30];
  const float* gng    = (const float*)d_in[31];
  const float* gnb    = (const float*)d_in[32];

  float* ws    = (float*)d_ws;
  float* HHb   = ws;                            // 1048576
  float* partial = ws + 1048576;                // 512
  float* weff  = ws + 1049088;                  // 2304
  float* gstat = ws + 1051392;                  // 128
  ushort_t* dsWbf  = (ushort_t*)(ws + 1051520); // 28672 shorts
  ushort_t* offAbf = (ushort_t*)(ws + 1065856); // 9216 shorts
  float* pstats= ws + 1070464;                  // 524288 -> ends 1594752
  float* outT  = ws + 1594752;                  // 4194304 -> ends 5789056
  ushort_t* outTbf = (ushort_t*)(ws + 5789056); // 4*128*130*64 shorts
  float* outb  = (float*)d_out;

  k_dwt0<<<512,512,0,stream>>>(x, dsw, offw, HHb, partial, dsWbf, offAbf);
  k_weff2<<<256,64,0,stream>>>(partial, weight, ratio,
    o1fc,o1g,o1b,o1m,o1v,o1cw,o1cb,o1fw,o1fb,
    o2fc,o2g,o2b,o2m,o2v,o2cw,o2cb,o2fw,o2fb,
    spw,spb, weff);
  k_iwtT<<<256,256,0,stream>>>(HHb, x, weff, outT, outTbf);
  k_dsfused<<<512,512,0,stream>>>(outT, outTbf, dsWbf, offAbf,
    offb, obg, obb, obm, obv, dsb, outb, pstats);
  k_gnfin2<<<64,256,0,stream>>>(pstats, gstat);
  k_gnapply<<<4096,256,0,stream>>>(outb, gstat, gng, gnb);
}

// Round 13
// 108.393 us; speedup vs baseline: 1.2500x; 1.2500x over previous
//
#include <hip/hip_runtime.h>
#include <math.h>

#define BB 4
#define CC 64
#define HH_ 128
#define WW 128
#define HPW (HH_*WW)     // 16384
#define KH 64
#define KW 64
#define KSZ 7
#define AA 16
#define EPSV 1e-5f
#define KTOT 448         // 7*64

typedef __attribute__((ext_vector_type(8))) short bf16x8;
typedef __attribute__((ext_vector_type(4))) float f32x4;
typedef unsigned short ushort_t;

__device__ __forceinline__ float sigm(float x){ return 1.0f/(1.0f+expf(-x)); }
__device__ __forceinline__ unsigned short f2bf(float f){
  unsigned u = __float_as_uint(f);
  return (unsigned short)((u + 0x7fffu + ((u>>16)&1u)) >> 16);
}

// ---------------- K1: prep + DWT-HH + mean partials (512 x 512) ----------------
__global__ __launch_bounds__(512) void k_dwt0(const float* __restrict__ x,
  const float* __restrict__ dsw, const float* __restrict__ offw,
  float* __restrict__ HHb, float* __restrict__ partial,
  ushort_t* __restrict__ dsWbf, ushort_t* __restrict__ offAbf)
{
  int t = threadIdx.x; int wg = blockIdx.x;
  int idx = wg*512 + t;
  if(idx < CC*KTOT){
    int co = idx/KTOT; int K = idx%KTOT; int k = K>>6; int ci = K&63;
    dsWbf[idx] = f2bf(dsw[(size_t)(co*CC+ci)*KSZ + k]);
  } else {
    int j2 = idx - CC*KTOT;
    if(j2 < 18*16*32){
      int kl = j2&31; int co = (j2>>5)&15; int s = j2>>9;
      int tap = s>>1; int ci = (s&1)*32 + kl;
      float v = 0.f;
      if(co<KSZ) v = offw[((size_t)co*CC + ci)*9 + tap];
      offAbf[j2] = f2bf(v);
    }
  }
  int lane = t&63, wid = t>>6;
  int e0 = wg*2048 + t*4;
  int bc = e0>>12; int h2 = (e0>>6)&63; int w0 = e0&63;
  const float* xp = x + (size_t)bc*HPW;
  float4 a0 = *(const float4*)(xp + (2*h2)*WW + 2*w0);
  float4 a1 = *(const float4*)(xp + (2*h2)*WW + 2*w0 + 4);
  float4 b0 = *(const float4*)(xp + (2*h2+1)*WW + 2*w0);
  float4 b1 = *(const float4*)(xp + (2*h2+1)*WW + 2*w0 + 4);
  float4 hh;
  hh.x = 0.5f*(a0.x - b0.x - a0.y + b0.y);
  hh.y = 0.5f*(a0.z - b0.z - a0.w + b0.w);
  hh.z = 0.5f*(a1.x - b1.x - a1.y + b1.y);
  hh.w = 0.5f*(a1.z - b1.z - a1.w + b1.w);
  *(float4*)(HHb + e0) = hh;
  float s = a0.x+a0.y+a0.z+a0.w + a1.x+a1.y+a1.z+a1.w
          + b0.x+b0.y+b0.z+b0.w + b1.x+b1.y+b1.z+b1.w;
  for(int o=32;o>0;o>>=1) s += __shfl_down(s,o);
  __shared__ float ls[8];
  if(lane==0) ls[wid] = s;
  __syncthreads();
  if(t==0){
    float tot=0.f;
    #pragma unroll
    for(int k2=0;k2<8;k2++) tot += ls[k2];
    partial[wg] = tot;
  }
}

// ---------------- K2: attention + weff, grid (b,o), 64 thr ----------------
__global__ __launch_bounds__(64) void k_weff2(const float* __restrict__ partial,
  const float* __restrict__ w, const float* __restrict__ ratio_p,
  const float* __restrict__ o1fc, const float* __restrict__ o1g,const float* __restrict__ o1b,
  const float* __restrict__ o1m,const float* __restrict__ o1v,
  const float* __restrict__ o1cw,const float* __restrict__ o1cb,
  const float* __restrict__ o1fw,const float* __restrict__ o1fb,
  const float* __restrict__ o2fc, const float* __restrict__ o2g,const float* __restrict__ o2b,
  const float* __restrict__ o2m,const float* __restrict__ o2v,
  const float* __restrict__ o2cw,const float* __restrict__ o2cb,
  const float* __restrict__ o2fw,const float* __restrict__ o2fb,
  const float* __restrict__ spw,const float* __restrict__ spb,
  float* __restrict__ weff)
{
  int bo = blockIdx.x; int b = bo>>6, o = bo&63; int ci = threadIdx.x;
  int bc = b*CC+ci;
  float g_own = (partial[2*bc] + partial[2*bc+1]) * (1.0f/HPW);
  float d1=o1cb[ci], d2=o1fb[ci], d3=o2cb[ci], d4=o2fb[ci];
  float sspacc[9];
  #pragma unroll
  for(int e=0;e<9;e++) sspacc[e]=spb[e];
  for(int j=0;j<AA;j++){
    float p1 = g_own * o1fc[j*CC+ci];
    float p2 = g_own * o2fc[j*CC+ci];
    #pragma unroll
    for(int off=32;off>0;off>>=1){ p1+=__shfl_xor(p1,off); p2+=__shfl_xor(p2,off); }
    p1 = (p1-o1m[j])*rsqrtf(o1v[j]+EPSV)*o1g[j]+o1b[j]; p1=fmaxf(p1,0.f);
    p2 = (p2-o2m[j])*rsqrtf(o2v[j]+EPSV)*o2g[j]+o2b[j]; p2=fmaxf(p2,0.f);
    d1 += p1*o1cw[ci*AA+j]; d2 += p1*o1fw[ci*AA+j];
    d3 += p2*o2cw[ci*AA+j]; d4 += p2*o2fw[ci*AA+j];
    #pragma unroll
    for(int e=0;e<9;e++) sspacc[e] += p2*spw[e*AA+j];
  }
  float sc1v=sigm(d1), sc2v=sigm(d3);
  float sf1o=__shfl(sigm(d2),o), sf2o=__shfl(sigm(d4),o);
  const float* wp = w + (size_t)(o*CC+ci)*9;
  float w9[9]; float m=0.f;
  #pragma unroll
  for(int e=0;e<9;e++){ w9[e]=wp[e]; m+=w9[e]; }
  m *= (1.0f/9.0f);
  float S1 = m * sc1v;
  float M[9];
  #pragma unroll
  for(int e=0;e<9;e++) M[e] = (w9[e]-m)*sc2v;
  #pragma unroll
  for(int off=32; off>0; off>>=1){
    S1 += __shfl_xor(S1, off);
    #pragma unroll
    for(int e=0;e<9;e++) M[e] += __shfl_xor(M[e], off);
  }
  if(ci==0){
    const float Dm[3][3] = {{2.f,2.f,2.f},{1.7320508075688772f,0.f,-1.7320508075688772f},{1.f,-2.f,1.f}};
    const float Di[3][3] = {{0.16666666666666666f,0.28867513459481287f,0.16666666666666666f},
                            {0.16666666666666666f,0.f,-0.3333333333333333f},
                            {0.16666666666666666f,-0.28867513459481287f,0.16666666666666666f}};
    float U[3][3], T[3][3], V[3][3], R[3][3];
    for(int k=0;k<3;k++)for(int n=0;n<3;n++) U[k][n]=Dm[k][0]*M[0*3+n]+Dm[k][1]*M[1*3+n]+Dm[k][2]*M[2*3+n];
    for(int k=0;k<3;k++)for(int l=0;l<3;l++) T[k][l]=(U[k][0]*Dm[l][0]+U[k][1]*Dm[l][1]+U[k][2]*Dm[l][2])*2.0f*sigm(sspacc[k*3+l]);
    for(int k=0;k<3;k++)for(int n=0;n<3;n++) V[k][n]=Di[k][0]*T[0][n]+Di[k][1]*T[1][n]+Di[k][2]*T[2][n];
    for(int k=0;k<3;k++)for(int l=0;l<3;l++) R[k][l]=V[k][0]*Di[l][0]+V[k][1]*Di[l][1]+V[k][2]*Di[l][2];
    float rr = ratio_p[0];
    float base = rr*4.0f*sf1o*S1;
    float w2f = (1.0f-rr)*4.0f*sf2o;
    #pragma unroll
    for(int e=0;e<9;e++) weff[(size_t)bo*9+e] = base + w2f*R[e/3][e%3];
  }
}

// ---------------- K3: iwt + transpose, 2 output rows per block ----------------
__global__ __launch_bounds__(256) void k_iwtT(const float* __restrict__ HHb,
  const float* __restrict__ x, const float* __restrict__ weff,
  float* __restrict__ outT, ushort_t* __restrict__ outTbf)
{
  __shared__ __align__(16) char smem[33024 + 16640];
  float* hs  = (float*)smem;             // [32][3][66]
  float* xt  = (float*)smem;             // [64][129] (reused after conv)
  float* d_s = (float*)(smem + 33024);   // [64][65]
  int wg = blockIdx.x; int b = wg>>6, h2 = wg&63;
  int t = threadIdx.x;
  #pragma unroll
  for(int half=0; half<2; ++half){
    for(int e=t; e<32*3*66; e+=256){
      int c_l = e/198; int rem = e - c_l*198; int r3 = rem/66; int wz = rem - r3*66;
      int r = h2 - 1 + r3; int w2 = wz - 1;
      int c = half*32 + c_l;
      float v = 0.f;
      if(r>=0 && r<KH && w2>=0 && w2<KW)
        v = HHb[((size_t)(b*CC+c))*(KH*KW) + r*KW + w2];
      hs[(c_l*3 + r3)*66 + wz] = v;
    }
    __syncthreads();
    {
      int c_l = t>>3, q = t&7;
      int c = half*32 + c_l;
      float wk[9];
      #pragma unroll
      for(int e=0;e<9;e++) wk[e] = weff[(size_t)(b*CC+c)*9+e];
      const float* hb = hs + c_l*198;
      #pragma unroll
      for(int j=0;j<8;j++){
        int w2 = q*8+j;
        float conv = 0.f;
        #pragma unroll
        for(int dh=0;dh<3;dh++){
          const float* hr = hb + dh*66 + w2;
          conv += wk[dh*3+0]*hr[0] + wk[dh*3+1]*hr[1] + wk[dh*3+2]*hr[2];
        }
        d_s[c*65+w2] = 0.5f*(conv - hb[1*66 + w2 + 1]);
      }
    }
    __syncthreads();
  }
  #pragma unroll
  for(int r=0;r<2;r++){
    int h = 2*h2 + r;
    for(int e=t; e<CC*WW; e+=256){
      int cc=e>>7, w=e&127;
      xt[cc*129+w] = x[((size_t)(b*CC+cc)*HH_+h)*WW + w];
    }
    __syncthreads();
    float* dst = outT + ((size_t)(b*HH_+h))*WW*CC;
    ushort_t* dstb = outTbf + ((size_t)(b*HH_+h))*130*CC;
    for(int e=t; e<CC*WW; e+=256){
      int w=e>>6, cc=e&63;
      float dv = d_s[cc*65+(w>>1)];
      float val = 2.f*xt[cc*129+w] + (((h + w)&1) ? -dv : dv);
      dst[e] = val;
      dstb[(w+1)*CC + cc] = f2bf(val);
    }
    if(t<128){ int cc=t&63; int side=t>>6; dstb[(size_t)side*129*CC + cc] = 0; }
    __syncthreads();
  }
}

// ---------------- K4: fused offset-conv + dy + deform-sample GEMM + GN partials ----------------
// block = (wseg, h, b) tile of 64 w; 256 thr / 4 waves; LDS ~25KB -> 4+ blocks/CU.
__global__ __launch_bounds__(256) void k_dsfused(const float* __restrict__ outT,
  const ushort_t* __restrict__ outTbf, const ushort_t* __restrict__ dsWbf,
  const ushort_t* __restrict__ offAbf, const float* __restrict__ offb,
  const float* __restrict__ obg, const float* __restrict__ obb,
  const float* __restrict__ obm, const float* __restrict__ obv,
  const float* __restrict__ dsb, float* __restrict__ yout, float* __restrict__ pstats)
{
  __shared__ ushort_t S2a[2*4096];       // 16KB: two [64 pos][64 ci] bf16 chunks
  __shared__ int sb0[KSZ*64], sb1[KSZ*64];
  __shared__ float swr[KSZ*64];
  __shared__ float off_s[KSZ*64];
  __shared__ float dy_s[KSZ*64];
  int t = threadIdx.x;
  int wg = blockIdx.x;
  int sw = (wg&7)*128 + (wg>>3);          // XCD swizzle over 1024 blocks
  int b = sw>>8, h = (sw>>1)&127, wseg = sw&1;
  int lane = t&63, wid = t>>6;
  int arow = lane&15, kgrp = lane>>4;
  // ---- Phase A: offset conv (4 waves, wave = one 16-wide w tile of the 64-seg) ----
  {
    f32x4 acc = (f32x4){0.f,0.f,0.f,0.f};
    #pragma unroll
    for(int s=0;s<18;s++){
      int tap = s>>1, chalf = s&1;
      int r = tap/3, dwp = tap%3;
      int hr = h - 1 + r;
      if(hr<0 || hr>=HH_) continue;
      bf16x8 aF = *(const bf16x8*)(offAbf + (s*16+arow)*32 + kgrp*8);
      const ushort_t* base = outTbf + ((size_t)(b*HH_+hr))*130*CC + chalf*32 + kgrp*8;
      int wp = wseg*64 + (wid<<4) + arow + dwp;
      bf16x8 bF = *(const bf16x8*)(base + (size_t)wp*CC);
      acc = __builtin_amdgcn_mfma_f32_16x16x32_bf16(aF, bF, acc, 0,0,0);
    }
    #pragma unroll
    for(int r=0;r<4;r++){
      int co = kgrp*4+r;
      if(co<KSZ) off_s[co*64 + (wid<<4) + arow] = acc[r];
    }
  }
  __syncthreads();
  // ---- Phase B: BN + tanh + cumsum ----
  if(t<64){
    int wl = t;
    float y[KSZ];
    #pragma unroll
    for(int k=0;k<KSZ;k++){
      float sc = obg[k]*rsqrtf(obv[k]+EPSV);
      float sh = obb[k]-obm[k]*sc;
      y[k] = tanhf((off_s[k*64+wl]+offb[k])*sc+sh);
    }
    dy_s[     wl]=y[0]+y[1]+y[2]; dy_s[64+wl]=y[1]+y[2]; dy_s[128+wl]=y[2];
    dy_s[192+wl]=0.f; dy_s[256+wl]=y[4]; dy_s[320+wl]=y[4]+y[5]; dy_s[384+wl]=y[4]+y[5]+y[6];
  }
  __syncthreads();
  // ---- Phase C: sample meta (7 x 64 tasks) ----
  for(int e=t; e<KSZ*64; e+=256){
    int k = e>>6, wl = e&63;
    int w = wseg*64 + wl;
    float dv = dy_s[e];
    float r = fminf(fmaxf((float)h + dv, 0.f), 127.f);
    float rf = floorf(r); int r0=(int)rf; float wr=r-rf; int r1=min(r0+1,127);
    int c = min(max(w+k-3,0),127);
    sb0[e] = ((b*HH_+r0)*WW+c)*CC;
    sb1[e] = ((b*HH_+r1)*WW+c)*CC;
    swr[e] = wr;
  }
  __syncthreads();
  // ---- Phase D: K-chunked double-buffered sample + MFMA GEMM ----
  // wave wid owns co-group wid*16; all 64 pos via 4 nt tiles.
  bf16x8 aF[14];
  {
    const ushort_t* Wp = dsWbf + (size_t)((wid<<4)+arow)*KTOT + kgrp*8;
    #pragma unroll
    for(int ks=0;ks<14;ks++) aF[ks] = *(const bf16x8*)(Wp + ks*32);
  }
  {
    ushort_t* buf = S2a;
    #pragma unroll
    for(int i=0;i<16;i++){
      int p = (wid<<4)+i;
      int b0=sb0[p], b1=sb1[p]; float wr=swr[p];
      float av = outT[b0+lane], c2 = outT[b1+lane];
      float v = av + wr*(c2-av);
      int idx = (p<<6)|lane;
      buf[idx ^ ((p&7)<<3)] = f2bf(v);
    }
  }
  __syncthreads();
  f32x4 acc[4];
  #pragma unroll
  for(int nt=0;nt<4;nt++) acc[nt] = (f32x4){0.f,0.f,0.f,0.f};
  int bufs = 0;
  for(int k=0;k<KSZ;k++){
    if(k+1<KSZ){
      ushort_t* nb = S2a + (bufs^1)*4096;
      #pragma unroll
      for(int i=0;i<16;i++){
        int p = (wid<<4)+i;
        int e = (k+1)*64 + p;
        int b0=sb0[e], b1=sb1[e]; float wr=swr[e];
        float av = outT[b0+lane], c2 = outT[b1+lane];
        float v = av + wr*(c2-av);
        int idx = (p<<6)|lane;
        nb[idx ^ ((p&7)<<3)] = f2bf(v);
      }
    }
    const ushort_t* cb = S2a + bufs*4096;
    #pragma unroll
    for(int nt=0;nt<4;nt++){
      int pos = (nt<<4) + arow;
      int i0 = (pos<<6) + kgrp*8;
      int sz = (pos&7)<<3;
      bf16x8 b0 = *(const bf16x8*)(cb + (i0 ^ sz));
      bf16x8 b1 = *(const bf16x8*)(cb + ((i0+32) ^ sz));
      acc[nt] = __builtin_amdgcn_mfma_f32_16x16x32_bf16(aF[2*k], b0, acc[nt], 0,0,0);
      acc[nt] = __builtin_amdgcn_mfma_f32_16x16x32_bf16(aF[2*k+1], b1, acc[nt], 0,0,0);
    }
    __syncthreads();
    bufs ^= 1;
  }
  // ---- epilogue: y + GN partials ----
  float vs[4]={0.f,0.f,0.f,0.f}, vq[4]={0.f,0.f,0.f,0.f};
  #pragma unroll
  for(int r=0;r<4;r++){
    int co = (wid<<4) + kgrp*4 + r;
    float bias = dsb[co];
    #pragma unroll
    for(int nt=0;nt<4;nt++){
      float y = acc[nt][r] + bias;
      int wcol = wseg*64 + (nt<<4) + arow;
      yout[((size_t)(b*CC+co)*HH_ + h)*WW + wcol] = y;
      vs[r] += y; vq[r] += y*y;
    }
  }
  #pragma unroll
  for(int m=1;m<16;m<<=1){
    #pragma unroll
    for(int r=0;r<4;r++){ vs[r]+=__shfl_xor(vs[r],m); vq[r]+=__shfl_xor(vq[r],m); }
  }
  if(arow==0){
    #pragma unroll
    for(int r=0;r<4;r++){
      int co = (wid<<4)+kgrp*4+r;
      int pi = (b*CC+co)*256 + h*2 + wseg;
      pstats[pi] = vs[r];
      pstats[65536+pi] = vq[r];
    }
  }
}

// ---------------- K5: reduce GN partials -> group stats ----------------
__global__ __launch_bounds__(256) void k_gnfin2(const float* __restrict__ pstats,
                                                float* __restrict__ gstat){
  int bg = blockIdx.x; int b = bg>>4, g = bg&15; int t = threadIdx.x;
  float s=0.f, q=0.f;
  #pragma unroll
  for(int c4=0;c4<4;c4++){
    int base = (b*CC + g*4+c4)*256;
    s += pstats[base + t];
    q += pstats[65536 + base + t];
  }
  for(int o=32;o>0;o>>=1){ s+=__shfl_down(s,o); q+=__shfl_down(q,o); }
  __shared__ float ls[4], lq[4];
  if((t&63)==0){ ls[t>>6]=s; lq[t>>6]=q; }
  __syncthreads();
  if(t==0){
    float S=ls[0]+ls[1]+ls[2]+ls[3], Q=lq[0]+lq[1]+lq[2]+lq[3];
    float inv = 1.0f/(4.0f*HPW);
    float mu = S*inv; float var = Q*inv - mu*mu;
    gstat[bg*2]=mu; gstat[bg*2+1]=rsqrtf(var+EPSV);
  }
}

// ---------------- K6: apply GN + affine + relu in place ----------------
__global__ void k_gnapply(float* __restrict__ y, const float* __restrict__ gstat,
  const float* __restrict__ gg, const float* __restrict__ gb){
  int idx = blockIdx.x*256 + threadIdx.x;
  float4* p = (float4*)y;
  int bc = idx >> 12;
  int b = bc>>6, c = bc&63;
  int gi = b*16 + (c>>2);
  float mu = gstat[gi*2], rstd = gstat[gi*2+1];
  float sc = rstd*gg[c], sh = gb[c]-mu*sc;
  float4 v = p[idx];
  v.x = fmaxf(v.x*sc+sh, 0.f);
  v.y = fmaxf(v.y*sc+sh, 0.f);
  v.z = fmaxf(v.z*sc+sh, 0.f);
  v.w = fmaxf(v.w*sc+sh, 0.f);
  p[idx] = v;
}

extern "C" void kernel_launch(void* const* d_in, const int* in_sizes, int n_in,
                              void* d_out, int out_size, void* d_ws, size_t ws_size,
                              hipStream_t stream) {
  const float* x      = (const float*)d_in[0];
  const float* weight = (const float*)d_in[1];
  const float* ratio  = (const float*)d_in[2];
  const float* o1fc   = (const float*)d_in[3];
  const float* o1g    = (const float*)d_in[4];
  const float* o1b    = (const float*)d_in[5];
  const float* o1m    = (const float*)d_in[6];
  const float* o1v    = (const float*)d_in[7];
  const float* o1cw   = (const float*)d_in[8];
  const float* o1cb   = (const float*)d_in[9];
  const float* o1fw   = (const float*)d_in[10];
  const float* o1fb   = (const float*)d_in[11];
  const float* o2fc   = (const float*)d_in[12];
  const float* o2g    = (const float*)d_in[13];
  const float* o2b    = (const float*)d_in[14];
  const float* o2m    = (const float*)d_in[15];
  const float* o2v    = (const float*)d_in[16];
  const float* o2cw   = (const float*)d_in[17];
  const float* o2cb   = (const float*)d_in[18];
  const float* o2fw   = (const float*)d_in[19];
  const float* o2fb   = (const float*)d_in[20];
  const float* spw    = (const float*)d_in[21];
  const float* spb    = (const float*)d_in[22];
  const float* offw   = (const float*)d_in[23];
  const float* offb   = (const float*)d_in[24];
  const float* obg    = (const float*)d_in[25];
  const float* obb    = (const float*)d_in[26];
  const float* obm    = (const float*)d_in[27];
  const float* obv    = (const float*)d_in[28];
  const float* dsw    = (const float*)d_in[29];
  const float* dsb    = (const float*)d_in[30];
  const float* gng    = (const float*)d_in[31];
  const float* gnb    = (const float*)d_in[32];

  float* ws    = (float*)d_ws;
  float* HHb   = ws;                            // 1048576
  float* partial = ws + 1048576;                // 512
  float* weff  = ws + 1049088;                  // 2304
  float* gstat = ws + 1051392;                  // 128
  ushort_t* dsWbf  = (ushort_t*)(ws + 1051520); // 28672 shorts
  ushort_t* offAbf = (ushort_t*)(ws + 1065856); // 9216 shorts
  float* pstats= ws + 1070464;                  // 131072
  float* outT  = ws + 1201536;                  // 4194304
  ushort_t* outTbf = (ushort_t*)(ws + 5395840); // 4*128*130*64 shorts
  float* outb  = (float*)d_out;

  k_dwt0<<<512,512,0,stream>>>(x, dsw, offw, HHb, partial, dsWbf, offAbf);
  k_weff2<<<256,64,0,stream>>>(partial, weight, ratio,
    o1fc,o1g,o1b,o1m,o1v,o1cw,o1cb,o1fw,o1fb,
    o2fc,o2g,o2b,o2m,o2v,o2cw,o2cb,o2fw,o2fb,
    spw,spb, weff);
  k_iwtT<<<256,256,0,stream>>>(HHb, x, weff, outT, outTbf);
  k_dsfused<<<1024,256,0,stream>>>(outT, outTbf, dsWbf, offAbf,
    offb, obg, obb, obm, obv, dsb, outb, pstats);
  k_gnfin2<<<64,256,0,stream>>>(pstats, gstat);
  k_gnapply<<<4096,256,0,stream>>>(outb, gstat, gng, gnb);
}

// Round 14
// 94.749 us; speedup vs baseline: 1.4300x; 1.1440x over previous
//
#include <hip/hip_runtime.h>
#include <math.h>

#define BB 4
#define CC 64
#define HH_ 128
#define WW 128
#define HPW (HH_*WW)     // 16384
#define KH 64
#define KW 64
#define KSZ 7
#define AA 16
#define EPSV 1e-5f
#define KTOT 448         // 7*64

typedef __attribute__((ext_vector_type(8))) short bf16x8;
typedef __attribute__((ext_vector_type(4))) float f32x4;
typedef unsigned short ushort_t;

__device__ __forceinline__ float sigm(float x){ return 1.0f/(1.0f+expf(-x)); }
__device__ __forceinline__ unsigned short f2bf(float f){
  unsigned u = __float_as_uint(f);
  return (unsigned short)((u + 0x7fffu + ((u>>16)&1u)) >> 16);
}

// ---------------- K1: prep + DWT-HH + mean partials (512 x 512) ----------------
__global__ __launch_bounds__(512) void k_dwt0(const float* __restrict__ x,
  const float* __restrict__ dsw, const float* __restrict__ offw,
  float* __restrict__ HHb, float* __restrict__ partial,
  ushort_t* __restrict__ dsWbf, ushort_t* __restrict__ offAbf)
{
  int t = threadIdx.x; int wg = blockIdx.x;
  int idx = wg*512 + t;
  if(idx < CC*KTOT){
    int co = idx/KTOT; int K = idx%KTOT; int k = K>>6; int ci = K&63;
    dsWbf[idx] = f2bf(dsw[(size_t)(co*CC+ci)*KSZ + k]);
  } else {
    int j2 = idx - CC*KTOT;
    if(j2 < 18*16*32){
      int kl = j2&31; int co = (j2>>5)&15; int s = j2>>9;
      int tap = s>>1; int ci = (s&1)*32 + kl;
      float v = 0.f;
      if(co<KSZ) v = offw[((size_t)co*CC + ci)*9 + tap];
      offAbf[j2] = f2bf(v);
    }
  }
  int lane = t&63, wid = t>>6;
  int e0 = wg*2048 + t*4;
  int bc = e0>>12; int h2 = (e0>>6)&63; int w0 = e0&63;
  const float* xp = x + (size_t)bc*HPW;
  float4 a0 = *(const float4*)(xp + (2*h2)*WW + 2*w0);
  float4 a1 = *(const float4*)(xp + (2*h2)*WW + 2*w0 + 4);
  float4 b0 = *(const float4*)(xp + (2*h2+1)*WW + 2*w0);
  float4 b1 = *(const float4*)(xp + (2*h2+1)*WW + 2*w0 + 4);
  float4 hh;
  hh.x = 0.5f*(a0.x - b0.x - a0.y + b0.y);
  hh.y = 0.5f*(a0.z - b0.z - a0.w + b0.w);
  hh.z = 0.5f*(a1.x - b1.x - a1.y + b1.y);
  hh.w = 0.5f*(a1.z - b1.z - a1.w + b1.w);
  *(float4*)(HHb + e0) = hh;
  float s = a0.x+a0.y+a0.z+a0.w + a1.x+a1.y+a1.z+a1.w
          + b0.x+b0.y+b0.z+b0.w + b1.x+b1.y+b1.z+b1.w;
  for(int o=32;o>0;o>>=1) s += __shfl_down(s,o);
  __shared__ float ls[8];
  if(lane==0) ls[wid] = s;
  __syncthreads();
  if(t==0){
    float tot=0.f;
    #pragma unroll
    for(int k2=0;k2<8;k2++) tot += ls[k2];
    partial[wg] = tot;
  }
}

// ---------------- K2: attention + weff, grid (b,o), 64 thr ----------------
__global__ __launch_bounds__(64) void k_weff2(const float* __restrict__ partial,
  const float* __restrict__ w, const float* __restrict__ ratio_p,
  const float* __restrict__ o1fc, const float* __restrict__ o1g,const float* __restrict__ o1b,
  const float* __restrict__ o1m,const float* __restrict__ o1v,
  const float* __restrict__ o1cw,const float* __restrict__ o1cb,
  const float* __restrict__ o1fw,const float* __restrict__ o1fb,
  const float* __restrict__ o2fc, const float* __restrict__ o2g,const float* __restrict__ o2b,
  const float* __restrict__ o2m,const float* __restrict__ o2v,
  const float* __restrict__ o2cw,const float* __restrict__ o2cb,
  const float* __restrict__ o2fw,const float* __restrict__ o2fb,
  const float* __restrict__ spw,const float* __restrict__ spb,
  float* __restrict__ weff)
{
  int bo = blockIdx.x; int b = bo>>6, o = bo&63; int ci = threadIdx.x;
  int bc = b*CC+ci;
  float g_own = (partial[2*bc] + partial[2*bc+1]) * (1.0f/HPW);
  float d1=o1cb[ci], d2=o1fb[ci], d3=o2cb[ci], d4=o2fb[ci];
  float sspacc[9];
  #pragma unroll
  for(int e=0;e<9;e++) sspacc[e]=spb[e];
  for(int j=0;j<AA;j++){
    float p1 = g_own * o1fc[j*CC+ci];
    float p2 = g_own * o2fc[j*CC+ci];
    #pragma unroll
    for(int off=32;off>0;off>>=1){ p1+=__shfl_xor(p1,off); p2+=__shfl_xor(p2,off); }
    p1 = (p1-o1m[j])*rsqrtf(o1v[j]+EPSV)*o1g[j]+o1b[j]; p1=fmaxf(p1,0.f);
    p2 = (p2-o2m[j])*rsqrtf(o2v[j]+EPSV)*o2g[j]+o2b[j]; p2=fmaxf(p2,0.f);
    d1 += p1*o1cw[ci*AA+j]; d2 += p1*o1fw[ci*AA+j];
    d3 += p2*o2cw[ci*AA+j]; d4 += p2*o2fw[ci*AA+j];
    #pragma unroll
    for(int e=0;e<9;e++) sspacc[e] += p2*spw[e*AA+j];
  }
  float sc1v=sigm(d1), sc2v=sigm(d3);
  float sf1o=__shfl(sigm(d2),o), sf2o=__shfl(sigm(d4),o);
  const float* wp = w + (size_t)(o*CC+ci)*9;
  float w9[9]; float m=0.f;
  #pragma unroll
  for(int e=0;e<9;e++){ w9[e]=wp[e]; m+=w9[e]; }
  m *= (1.0f/9.0f);
  float S1 = m * sc1v;
  float M[9];
  #pragma unroll
  for(int e=0;e<9;e++) M[e] = (w9[e]-m)*sc2v;
  #pragma unroll
  for(int off=32; off>0; off>>=1){
    S1 += __shfl_xor(S1, off);
    #pragma unroll
    for(int e=0;e<9;e++) M[e] += __shfl_xor(M[e], off);
  }
  if(ci==0){
    const float Dm[3][3] = {{2.f,2.f,2.f},{1.7320508075688772f,0.f,-1.7320508075688772f},{1.f,-2.f,1.f}};
    const float Di[3][3] = {{0.16666666666666666f,0.28867513459481287f,0.16666666666666666f},
                            {0.16666666666666666f,0.f,-0.3333333333333333f},
                            {0.16666666666666666f,-0.28867513459481287f,0.16666666666666666f}};
    float U[3][3], T[3][3], V[3][3], R[3][3];
    for(int k=0;k<3;k++)for(int n=0;n<3;n++) U[k][n]=Dm[k][0]*M[0*3+n]+Dm[k][1]*M[1*3+n]+Dm[k][2]*M[2*3+n];
    for(int k=0;k<3;k++)for(int l=0;l<3;l++) T[k][l]=(U[k][0]*Dm[l][0]+U[k][1]*Dm[l][1]+U[k][2]*Dm[l][2])*2.0f*sigm(sspacc[k*3+l]);
    for(int k=0;k<3;k++)for(int n=0;n<3;n++) V[k][n]=Di[k][0]*T[0][n]+Di[k][1]*T[1][n]+Di[k][2]*T[2][n];
    for(int k=0;k<3;k++)for(int l=0;l<3;l++) R[k][l]=V[k][0]*Di[l][0]+V[k][1]*Di[l][1]+V[k][2]*Di[l][2];
    float rr = ratio_p[0];
    float base = rr*4.0f*sf1o*S1;
    float w2f = (1.0f-rr)*4.0f*sf2o;
    #pragma unroll
    for(int e=0;e<9;e++) weff[(size_t)bo*9+e] = base + w2f*R[e/3][e%3];
  }
}

// ---------------- K3: iwt + transpose, 2 output rows per block ----------------
__global__ __launch_bounds__(256) void k_iwtT(const float* __restrict__ HHb,
  const float* __restrict__ x, const float* __restrict__ weff,
  float* __restrict__ outT, ushort_t* __restrict__ outTbf)
{
  __shared__ __align__(16) char smem[33024 + 16640];
  float* hs  = (float*)smem;             // [32][3][66]
  float* xt  = (float*)smem;             // [64][129] (reused after conv)
  float* d_s = (float*)(smem + 33024);   // [64][65]
  int wg = blockIdx.x; int b = wg>>6, h2 = wg&63;
  int t = threadIdx.x;
  #pragma unroll
  for(int half=0; half<2; ++half){
    for(int e=t; e<32*3*66; e+=256){
      int c_l = e/198; int rem = e - c_l*198; int r3 = rem/66; int wz = rem - r3*66;
      int r = h2 - 1 + r3; int w2 = wz - 1;
      int c = half*32 + c_l;
      float v = 0.f;
      if(r>=0 && r<KH && w2>=0 && w2<KW)
        v = HHb[((size_t)(b*CC+c))*(KH*KW) + r*KW + w2];
      hs[(c_l*3 + r3)*66 + wz] = v;
    }
    __syncthreads();
    {
      int c_l = t>>3, q = t&7;
      int c = half*32 + c_l;
      float wk[9];
      #pragma unroll
      for(int e=0;e<9;e++) wk[e] = weff[(size_t)(b*CC+c)*9+e];
      const float* hb = hs + c_l*198;
      #pragma unroll
      for(int j=0;j<8;j++){
        int w2 = q*8+j;
        float conv = 0.f;
        #pragma unroll
        for(int dh=0;dh<3;dh++){
          const float* hr = hb + dh*66 + w2;
          conv += wk[dh*3+0]*hr[0] + wk[dh*3+1]*hr[1] + wk[dh*3+2]*hr[2];
        }
        d_s[c*65+w2] = 0.5f*(conv - hb[1*66 + w2 + 1]);
      }
    }
    __syncthreads();
  }
  #pragma unroll
  for(int r=0;r<2;r++){
    int h = 2*h2 + r;
    for(int e=t; e<CC*WW; e+=256){
      int cc=e>>7, w=e&127;
      xt[cc*129+w] = x[((size_t)(b*CC+cc)*HH_+h)*WW + w];
    }
    __syncthreads();
    float* dst = outT + ((size_t)(b*HH_+h))*WW*CC;
    ushort_t* dstb = outTbf + ((size_t)(b*HH_+h))*130*CC;
    for(int e=t; e<CC*WW; e+=256){
      int w=e>>6, cc=e&63;
      float dv = d_s[cc*65+(w>>1)];
      float val = 2.f*xt[cc*129+w] + (((h + w)&1) ? -dv : dv);
      dst[e] = val;
      dstb[(w+1)*CC + cc] = f2bf(val);
    }
    if(t<128){ int cc=t&63; int side=t>>6; dstb[(size_t)side*129*CC + cc] = 0; }
    __syncthreads();
  }
}

// ---------------- K4: fused offset-conv + dy + deform-sample GEMM + GN partials ----------------
// r10 structure; gathers widened to float4/lane (16 lanes per sample row).
__global__ __launch_bounds__(512) void k_dsfused(const float* __restrict__ outT,
  const ushort_t* __restrict__ outTbf, const ushort_t* __restrict__ dsWbf,
  const ushort_t* __restrict__ offAbf, const float* __restrict__ offb,
  const float* __restrict__ obg, const float* __restrict__ obb,
  const float* __restrict__ obm, const float* __restrict__ obv,
  const float* __restrict__ dsb, float* __restrict__ yout, float* __restrict__ pstats)
{
  __shared__ ushort_t S2a[2*8192];
  __shared__ int sb0[KSZ*128], sb1[KSZ*128];
  __shared__ float swr[KSZ*128];
  __shared__ float off_s[KSZ*128];
  __shared__ float dy_s[KSZ*128];
  int t = threadIdx.x;
  int wg = blockIdx.x; int sw = (wg&7)*64 + (wg>>3);   // XCD swizzle
  int b = sw>>7, h = sw&127;
  int lane = t&63, wid = t>>6;
  int arow = lane&15, kgrp = lane>>4;
  // ---- Phase A: offset conv (8 waves, wave = one 16-wide w tile) ----
  {
    f32x4 acc = (f32x4){0.f,0.f,0.f,0.f};
    #pragma unroll
    for(int s=0;s<18;s++){
      int tap = s>>1, chalf = s&1;
      int r = tap/3, dwp = tap%3;
      int hr = h - 1 + r;
      if(hr<0 || hr>=HH_) continue;
      bf16x8 aF = *(const bf16x8*)(offAbf + (s*16+arow)*32 + kgrp*8);
      const ushort_t* base = outTbf + ((size_t)(b*HH_+hr))*130*CC + chalf*32 + kgrp*8;
      int wp = (wid<<4) + arow + dwp;
      bf16x8 bF = *(const bf16x8*)(base + (size_t)wp*CC);
      acc = __builtin_amdgcn_mfma_f32_16x16x32_bf16(aF, bF, acc, 0,0,0);
    }
    #pragma unroll
    for(int r=0;r<4;r++){
      int co = kgrp*4+r;
      if(co<KSZ) off_s[co*128 + (wid<<4) + arow] = acc[r];
    }
  }
  __syncthreads();
  // ---- Phase B: BN + tanh + cumsum ----
  if(t<128){
    int w = t;
    float y[KSZ];
    #pragma unroll
    for(int k=0;k<KSZ;k++){
      float sc = obg[k]*rsqrtf(obv[k]+EPSV);
      float sh = obb[k]-obm[k]*sc;
      y[k] = tanhf((off_s[k*128+w]+offb[k])*sc+sh);
    }
    dy_s[      w]=y[0]+y[1]+y[2]; dy_s[128+w]=y[1]+y[2]; dy_s[256+w]=y[2];
    dy_s[384+w]=0.f; dy_s[512+w]=y[4]; dy_s[640+w]=y[4]+y[5]; dy_s[768+w]=y[4]+y[5]+y[6];
  }
  __syncthreads();
  // ---- Phase C: sample meta ----
  for(int e=t; e<KSZ*128; e+=512){
    int k = e>>7, w = e&127;
    float dv = dy_s[e];
    float r = fminf(fmaxf((float)h + dv, 0.f), 127.f);
    float rf = floorf(r); int r0=(int)rf; float wr=r-rf; int r1=min(r0+1,127);
    int c = min(max(w+k-3,0),127);
    sb0[k*128+w] = ((b*HH_+r0)*WW+c)*CC;
    sb1[k*128+w] = ((b*HH_+r1)*WW+c)*CC;
    swr[k*128+w] = wr;
  }
  __syncthreads();
  // ---- Phase D: K-chunked double-buffered sample + MFMA GEMM (float4 gathers) ----
  int cg2 = wid&3, wh = wid>>2;
  int rsub = lane>>4;          // 0..3: row within 4-row group
  int ciq  = (lane&15)<<2;     // 0,4,...,60: ci quad
  // prologue: fill chunk 0
  {
    ushort_t* buf = S2a;
    #pragma unroll
    for(int i=0;i<4;i++){
      int p = (wid<<4) + i*4 + rsub;
      float4 v0 = *(const float4*)(outT + sb0[p] + ciq);
      float4 v1 = *(const float4*)(outT + sb1[p] + ciq);
      float wr = swr[p];
      unsigned lo = (unsigned)f2bf(v0.x + wr*(v1.x-v0.x)) | ((unsigned)f2bf(v0.y + wr*(v1.y-v0.y))<<16);
      unsigned hi = (unsigned)f2bf(v0.z + wr*(v1.z-v0.z)) | ((unsigned)f2bf(v0.w + wr*(v1.w-v0.w))<<16);
      int off = (p*128 + ciq*2) ^ ((p&7)<<4);
      *(uint2*)((char*)buf + off) = make_uint2(lo,hi);
    }
  }
  __syncthreads();
  f32x4 acc[4];
  #pragma unroll
  for(int nt=0;nt<4;nt++) acc[nt] = (f32x4){0.f,0.f,0.f,0.f};
  int bufs = 0;
  for(int k=0;k<KSZ;k++){
    // fill next chunk into other buffer (issues loads early; MFMAs below hide them)
    if(k+1<KSZ){
      ushort_t* nb = S2a + (bufs^1)*8192;
      #pragma unroll
      for(int i=0;i<4;i++){
        int p = (wid<<4) + i*4 + rsub;
        int e = (k+1)*128 + p;
        float4 v0 = *(const float4*)(outT + sb0[e] + ciq);
        float4 v1 = *(const float4*)(outT + sb1[e] + ciq);
        float wr = swr[e];
        unsigned lo = (unsigned)f2bf(v0.x + wr*(v1.x-v0.x)) | ((unsigned)f2bf(v0.y + wr*(v1.y-v0.y))<<16);
        unsigned hi = (unsigned)f2bf(v0.z + wr*(v1.z-v0.z)) | ((unsigned)f2bf(v0.w + wr*(v1.w-v0.w))<<16);
        int off = (p*128 + ciq*2) ^ ((p&7)<<4);
        *(uint2*)((char*)nb + off) = make_uint2(lo,hi);
      }
    }
    // MFMAs for current chunk
    const ushort_t* cb = S2a + bufs*8192;
    #pragma unroll
    for(int nt=0;nt<4;nt++){
      int pos = (wh<<6) + (nt<<4) + arow;
      int i0 = (pos<<6) + kgrp*8;
      int sz = (pos&7)<<3;
      bf16x8 b0 = *(const bf16x8*)(cb + (i0 ^ sz));
      bf16x8 b1 = *(const bf16x8*)(cb + ((i0+32) ^ sz));
      const ushort_t* Wp = dsWbf + (size_t)((cg2<<4)+arow)*KTOT + (k<<6) + kgrp*8;
      bf16x8 a0 = *(const bf16x8*)Wp;
      bf16x8 a1 = *(const bf16x8*)(Wp+32);
      acc[nt] = __builtin_amdgcn_mfma_f32_16x16x32_bf16(a0, b0, acc[nt], 0,0,0);
      acc[nt] = __builtin_amdgcn_mfma_f32_16x16x32_bf16(a1, b1, acc[nt], 0,0,0);
    }
    __syncthreads();
    bufs ^= 1;
  }
  // ---- epilogue: y + GN partials ----
  float vs[4]={0.f,0.f,0.f,0.f}, vq[4]={0.f,0.f,0.f,0.f};
  #pragma unroll
  for(int r=0;r<4;r++){
    int co = (cg2<<4) + kgrp*4 + r;
    float bias = dsb[co];
    #pragma unroll
    for(int nt=0;nt<4;nt++){
      float y = acc[nt][r] + bias;
      int wcol = (wh<<6) + (nt<<4) + arow;
      yout[((size_t)(b*CC+co)*HH_ + h)*WW + wcol] = y;
      vs[r] += y; vq[r] += y*y;
    }
  }
  #pragma unroll
  for(int m=1;m<16;m<<=1){
    #pragma unroll
    for(int r=0;r<4;r++){ vs[r]+=__shfl_xor(vs[r],m); vq[r]+=__shfl_xor(vq[r],m); }
  }
  if(arow==0){
    #pragma unroll
    for(int r=0;r<4;r++){
      int co = (cg2<<4)+kgrp*4+r;
      int pi = (b*CC+co)*256 + h*2 + wh;
      pstats[pi] = vs[r];
      pstats[65536+pi] = vq[r];
    }
  }
}

// ---------------- K5: reduce GN partials -> group stats ----------------
__global__ __launch_bounds__(256) void k_gnfin2(const float* __restrict__ pstats,
                                                float* __restrict__ gstat){
  int bg = blockIdx.x; int b = bg>>4, g = bg&15; int t = threadIdx.x;
  float s=0.f, q=0.f;
  #pragma unroll
  for(int c4=0;c4<4;c4++){
    int base = (b*CC + g*4+c4)*256;
    s += pstats[base + t];
    q += pstats[65536 + base + t];
  }
  for(int o=32;o>0;o>>=1){ s+=__shfl_down(s,o); q+=__shfl_down(q,o); }
  __shared__ float ls[4], lq[4];
  if((t&63)==0){ ls[t>>6]=s; lq[t>>6]=q; }
  __syncthreads();
  if(t==0){
    float S=ls[0]+ls[1]+ls[2]+ls[3], Q=lq[0]+lq[1]+lq[2]+lq[3];
    float inv = 1.0f/(4.0f*HPW);
    float mu = S*inv; float var = Q*inv - mu*mu;
    gstat[bg*2]=mu; gstat[bg*2+1]=rsqrtf(var+EPSV);
  }
}

// ---------------- K6: apply GN + affine + relu in place ----------------
__global__ void k_gnapply(float* __restrict__ y, const float* __restrict__ gstat,
  const float* __restrict__ gg, const float* __restrict__ gb){
  int idx = blockIdx.x*256 + threadIdx.x;
  float4* p = (float4*)y;
  int bc = idx >> 12;
  int b = bc>>6, c = bc&63;
  int gi = b*16 + (c>>2);
  float mu = gstat[gi*2], rstd = gstat[gi*2+1];
  float sc = rstd*gg[c], sh = gb[c]-mu*sc;
  float4 v = p[idx];
  v.x = fmaxf(v.x*sc+sh, 0.f);
  v.y = fmaxf(v.y*sc+sh, 0.f);
  v.z = fmaxf(v.z*sc+sh, 0.f);
  v.w = fmaxf(v.w*sc+sh, 0.f);
  p[idx] = v;
}

extern "C" void kernel_launch(void* const* d_in, const int* in_sizes, int n_in,
                              void* d_out, int out_size, void* d_ws, size_t ws_size,
                              hipStream_t stream) {
  const float* x      = (const float*)d_in[0];
  const float* weight = (const float*)d_in[1];
  const float* ratio  = (const float*)d_in[2];
  const float* o1fc   = (const float*)d_in[3];
  const float* o1g    = (const float*)d_in[4];
  const float* o1b    = (const float*)d_in[5];
  const float* o1m    = (const float*)d_in[6];
  const float* o1v    = (const float*)d_in[7];
  const float* o1cw   = (const float*)d_in[8];
  const float* o1cb   = (const float*)d_in[9];
  const float* o1fw   = (const float*)d_in[10];
  const float* o1fb   = (const float*)d_in[11];
  const float* o2fc   = (const float*)d_in[12];
  const float* o2g    = (const float*)d_in[13];
  const float* o2b    = (const float*)d_in[14];
  const float* o2m    = (const float*)d_in[15];
  const float* o2v    = (const float*)d_in[16];
  const float* o2cw   = (const float*)d_in[17];
  const float* o2cb   = (const float*)d_in[18];
  const float* o2fw   = (const float*)d_in[19];
  const float* o2fb   = (const float*)d_in[20];
  const float* spw    = (const float*)d_in[21];
  const float* spb    = (const float*)d_in[22];
  const float* offw   = (const float*)d_in[23];
  const float* offb   = (const float*)d_in[24];
  const float* obg    = (const float*)d_in[25];
  const float* obb    = (const float*)d_in[26];
  const float* obm    = (const float*)d_in[27];
  const float* obv    = (const float*)d_in[28];
  const float* dsw    = (const float*)d_in[29];
  const float* dsb    = (const float*)d_in[30];
  const float* gng    = (const float*)d_in[31];
  const float* gnb    = (const float*)d_in[32];

  float* ws    = (float*)d_ws;
  float* HHb   = ws;                            // 1048576
  float* partial = ws + 1048576;                // 512
  float* weff  = ws + 1049088;                  // 2304
  float* gstat = ws + 1051392;                  // 128
  ushort_t* dsWbf  = (ushort_t*)(ws + 1051520); // 28672 shorts
  ushort_t* offAbf = (ushort_t*)(ws + 1065856); // 9216 shorts
  float* pstats= ws + 1070464;                  // 131072
  float* outT  = ws + 1201536;                  // 4194304
  ushort_t* outTbf = (ushort_t*)(ws + 5395840); // 4*128*130*64 shorts
  float* outb  = (float*)d_out;

  k_dwt0<<<512,512,0,stream>>>(x, dsw, offw, HHb, partial, dsWbf, offAbf);
  k_weff2<<<256,64,0,stream>>>(partial, weight, ratio,
    o1fc,o1g,o1b,o1m,o1v,o1cw,o1cb,o1fw,o1fb,
    o2fc,o2g,o2b,o2m,o2v,o2cw,o2cb,o2fw,o2fb,
    spw,spb, weff);
  k_iwtT<<<256,256,0,stream>>>(HHb, x, weff, outT, outTbf);
  k_dsfused<<<512,512,0,stream>>>(outT, outTbf, dsWbf, offAbf,
    offb, obg, obb, obm, obv, dsb, outb, pstats);
  k_gnfin2<<<64,256,0,stream>>>(pstats, gstat);
  k_gnapply<<<4096,256,0,stream>>>(outb, gstat, gng, gnb);
}